// Round 11
// baseline (1009.264 us; speedup 1.0000x reference)
//
#include <hip/hip_runtime.h>
#include <cstdint>
#include <cstddef>

typedef unsigned short u16;
typedef unsigned int u32;

typedef unsigned short u16x8 __attribute__((ext_vector_type(8)));
typedef __bf16 bf16x8 __attribute__((ext_vector_type(8)));
typedef float f32x4 __attribute__((ext_vector_type(4)));
typedef float f32x8 __attribute__((ext_vector_type(8)));

#define NB   128
#define NL   192
#define NTOK (NB * NL)   // 24576
#define DIM  512
#define HID  2048
#define PM   48          // fused-FFN panel rows; NTOK/PM = 512 blocks = 2 CU rounds

static __device__ __forceinline__ float bf2f(u16 h) {
    union { u32 u; float f; } v; v.u = ((u32)h) << 16; return v.f;
}
static __device__ __forceinline__ u16 f2bf(float f) {
    union { float f; u32 u; } v; v.f = f;
    u32 u = v.u + 0x7FFF + ((v.u >> 16) & 1);  // RNE
    return (u16)(u >> 16);
}

// -------- weight transpose + cast: in f32 (K,N) -> out bf16 (N,K) --------
__global__ void transpose_f2b(const float* __restrict__ in, u16* __restrict__ out,
                              int K, int N) {
    __shared__ float tile[32][33];
    int tx = threadIdx.x & 31, ty = threadIdx.x >> 5;  // 32 x 8
    int n0 = blockIdx.x * 32, k0 = blockIdx.y * 32;
#pragma unroll
    for (int i = 0; i < 4; i++)
        tile[ty + i * 8][tx] = in[(size_t)(k0 + ty + i * 8) * N + n0 + tx];
    __syncthreads();
#pragma unroll
    for (int i = 0; i < 4; i++)
        out[(size_t)(n0 + ty + i * 8) * K + k0 + tx] = f2bf(tile[tx][ty + i * 8]);
}

// -------- embedding: emb[t=l*B+b][d] = sum of 5 f32 tables ----
static __device__ __forceinline__ void add8f(float* acc, const float* p) {
    f32x8 v = *(const f32x8*)p;
#pragma unroll
    for (int i = 0; i < 8; i++) acc[i] += v[i];
}

__global__ void embed_kernel(const int* __restrict__ element, const int* __restrict__ aroma,
                             const int* __restrict__ charge, const int* __restrict__ segment,
                             const float* __restrict__ pe, const float* __restrict__ E_elem,
                             const float* __restrict__ E_charge, const float* __restrict__ E_aroma,
                             const float* __restrict__ E_seg,
                             float* __restrict__ emb32, u16* __restrict__ emb16) {
    int t = blockIdx.x * 4 + (threadIdx.x >> 6);  // one wave per token
    int lane = threadIdx.x & 63;
    int l = t >> 7, b = t & 127;                  // t = l*128 + b
    int d = lane * 8;
    int idx = b * NL + l;
    int e = element[idx];
    int a = aroma[idx];
    int c = charge[idx] + 6;
    int s = segment[idx];
    float acc[8] = {0, 0, 0, 0, 0, 0, 0, 0};
    add8f(acc, E_elem  + (size_t)e * DIM + d);
    add8f(acc, pe      + (size_t)l * DIM + d);
    add8f(acc, E_aroma + (size_t)a * DIM + d);
    add8f(acc, E_charge+ (size_t)c * DIM + d);
    add8f(acc, E_seg   + (size_t)s * DIM + d);
    f32x8 o32; u16x8 o16;
#pragma unroll
    for (int i = 0; i < 8; i++) { o32[i] = acc[i]; o16[i] = f2bf(acc[i]); }
    *(f32x8*)(emb32 + (size_t)t * DIM + d) = o32;
    *(u16x8*)(emb16 + (size_t)t * DIM + d) = o16;
}

// ======================= fused FFN v3 (+optional W5) =======================
// Per 48-row panel of X [M][512] bf16:
//   h_j  = relu(X @ WaT_j^T + ba_j)   (j = 8 slices of 256 hidden)
//   acc2 = sum_j h_j @ WbT_j^T ; out = acc2 + bb + resid
//   if WcT: xb = out kept in LDS; OUT = xb @ WcT^T + bc  (W5 fold)
// v3 fix over r10 (300 us, MfmaUtil 15%): weights are NOT fetched as direct
// global B-frags (TA-bound, latency in MFMA dep chain). They stream through
// LDS as uniform 32 KB chunks, double-buffered, with the round-3-proven
// one-vmcnt(0)+s_barrier-per-step loop: stage chunk n+1 at the top of step n
// (full-step issue->wait distance covers the ~300cy L2-hot latency).
// Chunk sequence per block (K1): [j: Wa(j,0..7) then Wb(j,0..7)] x 8 = 128;
// K2 appends Wc(0..15) after the in-LDS xb update. Stage-next map: G1 kt<7 ->
// Wa(j,kt+1); kt=7 -> Wb(j,0); G2 s<7 -> Wb(j,s+1); s=7 -> Wa(j+1,0) or Wc(0).
// Buffer safety = round-3 argument: step n reads buf n&1; buf (n+1)&1's last
// readers (step n-1) finished before step n's barrier; stage issued after it.
// Layouts (bank-analyzed, all reads <=2-way = free):
//   xs [48][512] XOR-swz (r10-proven): slot c holds logical chunk c^(row&7).
//   Wa chunk 256 rows x 64k, CHUNK-MAJOR: lds[(c*256+r)*8], c=0..7 (16B units)
//   Wb/Wc chunk 512 rows x 32k, chunk-major: lds[(c*512+r)*8], c=0..3
//   h [48][264] XOR-swz on 8-u16 chunks.
// Waves: 8 x (1M x 8N). G1: wave = 48x32, acc1[3][2]; G2/G3: 48x64, acc[3][4].
__global__ __launch_bounds__(512, 2) void ffn_fused(
    const u16* __restrict__ X,          // [M][512] bf16 row-major
    const float* __restrict__ resid32,  // [M][512] f32 (emb32) or nullptr
    const u16* __restrict__ WaT,        // [2048][512] bf16
    const float* __restrict__ ba,       // [2048]
    const u16* __restrict__ WbT,        // [512][2048] bf16
    const float* __restrict__ bb,       // [512]
    const u16* __restrict__ WcT,        // [512][512] bf16 or nullptr
    const float* __restrict__ bc,       // [512] or nullptr
    u16* __restrict__ OUT) {            // [M][512] bf16
    __shared__ __align__(16) u16 xs[PM * 512];     // 48 KB  x panel (later xb)
    __shared__ __align__(16) u16 wbuf[2 * 16384];  // 64 KB  weight chunk dbuf
    __shared__ __align__(16) u16 hsm[PM * 264];    // 24.75 KB h / epilogue

    const int tid  = threadIdx.x;
    const int wave = tid >> 6;       // n-group 0..7
    const int lane = tid & 63;
    const int fr   = lane & 15;
    const int fq   = lane >> 4;

    const int bid = blockIdx.x;      // 512 blocks, %8==0 -> bijective swizzle
    const int wg  = (bid & 7) * (gridDim.x >> 3) + (bid >> 3);
    const int m0  = wg * PM;

#define GLL(gp, lp) __builtin_amdgcn_global_load_lds(                            \
        (const __attribute__((address_space(1))) void*)(gp),                     \
        (__attribute__((address_space(3))) void*)(lp), 16, 0, 0)

    // ---- prologue: stage x panel (6 GLL) + Wa(0,0) (4 GLL) ----
#pragma unroll
    for (int g = 0; g < 6; ++g) {
        int u = g * 512 + tid, row = u >> 6, c = u & 63;
        GLL(X + (size_t)(m0 + row) * 512 + ((c ^ (row & 7)) * 8), &xs[u * 8]);
    }
#define STG_WA(bf, j, kt) do {                                                   \
    _Pragma("unroll") for (int g = 0; g < 4; ++g) {                              \
        int u = g * 512 + tid, c = u >> 8, r = u & 255;                          \
        GLL(WaT + (size_t)((j) * 256 + r) * 512 + (kt) * 64 + c * 8,             \
            &wbuf[(bf) * 16384 + u * 8]);                                        \
    } } while (0)
#define STG_WB(bf, j, s) do {                                                    \
    _Pragma("unroll") for (int g = 0; g < 4; ++g) {                              \
        int u = g * 512 + tid, c = u >> 9, r = u & 511;                          \
        GLL(WbT + (size_t)r * 2048 + (j) * 256 + (s) * 32 + c * 8,               \
            &wbuf[(bf) * 16384 + u * 8]);                                        \
    } } while (0)
#define STG_WC(bf, s) do {                                                       \
    _Pragma("unroll") for (int g = 0; g < 4; ++g) {                              \
        int u = g * 512 + tid, c = u >> 9, r = u & 511;                          \
        GLL(WcT + (size_t)r * 512 + (s) * 32 + c * 8,                            \
            &wbuf[(bf) * 16384 + u * 8]);                                        \
    } } while (0)
#define VMB() asm volatile("s_waitcnt vmcnt(0)\n\ts_barrier" ::: "memory")

    STG_WA(0, 0, 0);

    int buf = 0;
    f32x4 acc2[3][4] = {};

    for (int j = 0; j < 8; ++j) {
        // ---------- G1: 8 steps (kt), out 48x256 slice, acc1[3][2] ----------
        f32x4 acc1[3][2] = {};
        for (int kt = 0; kt < 8; ++kt) {
            VMB();
            if (kt < 7) STG_WA(buf ^ 1, j, kt + 1);
            else        STG_WB(buf ^ 1, j, 0);
            const u16* W = &wbuf[buf * 16384];
            bf16x8 afr[3][2], bfr[2][2];
#pragma unroll
            for (int i = 0; i < 3; ++i)
#pragma unroll
                for (int ks = 0; ks < 2; ++ks) {
                    int q = kt * 8 + ks * 4 + fq;
                    afr[i][ks] = *(const bf16x8*)&xs[(i * 16 + fr) * 512 + ((q ^ (fr & 7)) * 8)];
                }
#pragma unroll
            for (int j2 = 0; j2 < 2; ++j2)
#pragma unroll
                for (int ks = 0; ks < 2; ++ks)
                    bfr[j2][ks] = *(const bf16x8*)&W[((ks * 4 + fq) * 256 + wave * 32 + j2 * 16 + fr) * 8];
            __builtin_amdgcn_s_setprio(1);
#pragma unroll
            for (int ks = 0; ks < 2; ++ks)
#pragma unroll
                for (int i = 0; i < 3; ++i)
#pragma unroll
                    for (int j2 = 0; j2 < 2; ++j2)
                        acc1[i][j2] = __builtin_amdgcn_mfma_f32_16x16x32_bf16(
                            afr[i][ks], bfr[j2][ks], acc1[i][j2], 0, 0, 0);
            __builtin_amdgcn_s_setprio(0);
            buf ^= 1;
        }
        // ---------- h write: relu + ba (XOR-swz), sync ----------
#pragma unroll
        for (int j2 = 0; j2 < 2; ++j2) {
            int col = wave * 32 + j2 * 16 + fr;
            float bv = ba[j * 256 + col];
#pragma unroll
            for (int i = 0; i < 3; ++i)
#pragma unroll
                for (int r = 0; r < 4; ++r) {
                    int row = i * 16 + fq * 4 + r;
                    hsm[row * 264 + (((col >> 3) ^ (row & 7)) * 8) + (col & 7)]
                        = f2bf(fmaxf(acc1[i][j2][r] + bv, 0.0f));
                }
        }
        __syncthreads();
        // ---------- G2: 8 steps (s), acc2 += h_j @ WbT_j^T ----------
        for (int s = 0; s < 8; ++s) {
            VMB();
            if (s < 7)       STG_WB(buf ^ 1, j, s + 1);
            else if (j < 7)  STG_WA(buf ^ 1, j + 1, 0);
            else if (WcT)    STG_WC(buf ^ 1, 0);
            const u16* W = &wbuf[buf * 16384];
            bf16x8 afr[3], bfr[4];
#pragma unroll
            for (int i = 0; i < 3; ++i) {
                int q = s * 4 + fq;
                afr[i] = *(const bf16x8*)&hsm[(i * 16 + fr) * 264 + ((q ^ (fr & 7)) * 8)];
            }
#pragma unroll
            for (int j2 = 0; j2 < 4; ++j2)
                bfr[j2] = *(const bf16x8*)&W[(fq * 512 + wave * 64 + j2 * 16 + fr) * 8];
            __builtin_amdgcn_s_setprio(1);
#pragma unroll
            for (int i = 0; i < 3; ++i)
#pragma unroll
                for (int j2 = 0; j2 < 4; ++j2)
                    acc2[i][j2] = __builtin_amdgcn_mfma_f32_16x16x32_bf16(
                        afr[i], bfr[j2], acc2[i][j2], 0, 0, 0);
            __builtin_amdgcn_s_setprio(0);
            buf ^= 1;
        }
    }

    if (!WcT) {
        // ---------- K1 epilogue: OUT = acc2 + bb + resid32 (two passes) -----
#pragma unroll
        for (int p = 0; p < 2; ++p) {
            __syncthreads();
            if ((wave >> 2) == p) {
#pragma unroll
                for (int j2 = 0; j2 < 4; ++j2) {
                    int col = wave * 64 + j2 * 16 + fr;
                    float bv = bb[col];
#pragma unroll
                    for (int i = 0; i < 3; ++i)
#pragma unroll
                        for (int r = 0; r < 4; ++r) {
                            int row = i * 16 + fq * 4 + r;
                            float v = acc2[i][j2][r] + bv
                                    + resid32[(size_t)(m0 + row) * 512 + col];
                            hsm[row * 264 + (col - p * 256)] = f2bf(v);
                        }
                }
            }
            __syncthreads();
#pragma unroll
            for (int g = 0; g < 3; ++g) {
                int u = g * 512 + tid, row = u >> 5, c = u & 31;
                *(u16x8*)(OUT + (size_t)(m0 + row) * 512 + p * 256 + c * 8) =
                    *(const u16x8*)&hsm[row * 264 + c * 8];
            }
        }
        return;
    }

    // ---------- K2: xb = acc2 + bb + x, in place in xs ----------
    __syncthreads();
#pragma unroll
    for (int j2 = 0; j2 < 4; ++j2) {
        int col = wave * 64 + j2 * 16 + fr;
        float bv = bb[col];
        int q = col >> 3, lo = col & 7;
#pragma unroll
        for (int i = 0; i < 3; ++i)
#pragma unroll
            for (int r = 0; r < 4; ++r) {
                int row = i * 16 + fq * 4 + r;
                int xi = row * 512 + ((q ^ (row & 7)) * 8) + lo;
                xs[xi] = f2bf(acc2[i][j2][r] + bv + bf2f(xs[xi]));
            }
    }
    __syncthreads();
    // ---------- G3: 16 steps, OUT = xb @ WcT^T + bc ----------
    f32x4 acc3[3][4] = {};
    for (int s = 0; s < 16; ++s) {
        VMB();
        if (s < 15) STG_WC(buf ^ 1, s + 1);
        const u16* W = &wbuf[buf * 16384];
        bf16x8 afr[3], bfr[4];
#pragma unroll
        for (int i = 0; i < 3; ++i) {
            int q = s * 4 + fq;
            afr[i] = *(const bf16x8*)&xs[(i * 16 + fr) * 512 + ((q ^ (fr & 7)) * 8)];
        }
#pragma unroll
        for (int j2 = 0; j2 < 4; ++j2)
            bfr[j2] = *(const bf16x8*)&W[(fq * 512 + wave * 64 + j2 * 16 + fr) * 8];
        __builtin_amdgcn_s_setprio(1);
#pragma unroll
        for (int i = 0; i < 3; ++i)
#pragma unroll
            for (int j2 = 0; j2 < 4; ++j2)
                acc3[i][j2] = __builtin_amdgcn_mfma_f32_16x16x32_bf16(
                    afr[i], bfr[j2], acc3[i][j2], 0, 0, 0);
        __builtin_amdgcn_s_setprio(0);
        buf ^= 1;
    }
    // ---------- K2 epilogue: OUT = acc3 + bc ----------
#pragma unroll
    for (int p = 0; p < 2; ++p) {
        __syncthreads();
        if ((wave >> 2) == p) {
#pragma unroll
            for (int j2 = 0; j2 < 4; ++j2) {
                int col = wave * 64 + j2 * 16 + fr;
                float bv = bc[col];
#pragma unroll
                for (int i = 0; i < 3; ++i)
#pragma unroll
                    for (int r = 0; r < 4; ++r) {
                        int row = i * 16 + fq * 4 + r;
                        hsm[row * 264 + (col - p * 256)] = f2bf(acc3[i][j2][r] + bv);
                    }
            }
        }
        __syncthreads();
#pragma unroll
        for (int g = 0; g < 3; ++g) {
            int u = g * 512 + tid, row = u >> 5, c = u & 31;
            *(u16x8*)(OUT + (size_t)(m0 + row) * 512 + p * 256 + c * 8) =
                *(const u16x8*)&hsm[row * 264 + c * 8];
        }
    }
#undef STG_WA
#undef STG_WB
#undef STG_WC
#undef VMB
#undef GLL
}

// -------- aggregation + final residual (in-place on d_out, f32) --------
__global__ void agg_kernel(const float* __restrict__ emb32, const u16* __restrict__ msg,
                           const int* __restrict__ bond, float* __restrict__ out) {
    int t = blockIdx.x * 4 + (threadIdx.x >> 6);  // one wave per token
    int lane = threadIdx.x & 63;
    int l = t >> 7, b = t & 127;
    int d = lane * 8;
    float acc[8];
    {
        f32x8 v = *(const f32x8*)(emb32 + (size_t)t * DIM + d);
#pragma unroll
        for (int i = 0; i < 8; i++) acc[i] = v[i];
    }
    const int* bp = bond + ((size_t)b * NL + l) * 6;
#pragma unroll
    for (int m = 0; m < 6; m++) {
        int j = bp[m];
        if (j != l) {  // wave-uniform branch
            u16x8 g = *(const u16x8*)(msg + ((size_t)j * NB + b) * DIM + d);
#pragma unroll
            for (int i = 0; i < 8; i++) acc[i] += bf2f(g[i]);
        }
    }
    f32x8 o;
#pragma unroll
    for (int i = 0; i < 8; i++) o[i] = acc[i];
    *(f32x8*)(out + (size_t)t * DIM + d) = o;
}

extern "C" void kernel_launch(void* const* d_in, const int* in_sizes, int n_in,
                              void* d_out, int out_size, void* d_ws, size_t ws_size,
                              hipStream_t stream) {
    const int* element = (const int*)d_in[0];
    const int* bond    = (const int*)d_in[1];
    const int* aroma   = (const int*)d_in[2];
    const int* charge  = (const int*)d_in[3];
    const int* segment = (const int*)d_in[4];
    const float* pe      = (const float*)d_in[5];
    const float* E_elem  = (const float*)d_in[6];
    const float* E_charge= (const float*)d_in[7];
    const float* E_aroma = (const float*)d_in[8];
    const float* E_seg   = (const float*)d_in[9];
    const float* W1 = (const float*)d_in[10];
    const float* b1 = (const float*)d_in[11];
    const float* W2 = (const float*)d_in[12];
    const float* b2 = (const float*)d_in[13];
    const float* W3 = (const float*)d_in[14];
    const float* b3 = (const float*)d_in[15];
    const float* W4 = (const float*)d_in[16];
    const float* b4 = (const float*)d_in[17];
    const float* W5 = (const float*)d_in[18];
    const float* b5 = (const float*)d_in[19];

    // f32 emb lives in d_out (50 MiB); agg rewrites d_out in place at the end.
    float* emb32 = (float*)d_out;

    // dynamic ws layout — never exceed ws_size
    char* ws = (char*)d_ws;
    size_t woff = 0;
    auto take = [&](size_t bytes) -> u16* {
        u16* p = (u16*)(ws + woff);
        woff += (bytes + 255) & ~(size_t)255;
        return p;
    };
    u16* W1T = take((size_t)HID * DIM * 2);   // 2048x512 bf16
    u16* W2T = take((size_t)DIM * HID * 2);   // 512x2048
    u16* W3T = take((size_t)HID * DIM * 2);
    u16* W4T = take((size_t)DIM * HID * 2);
    u16* W5T = take((size_t)DIM * DIM * 2);
    u16* emb16 = take((size_t)NTOK * DIM * 2);  // 24 MiB
    u16* xa    = take((size_t)NTOK * DIM * 2);  // 24 MiB
    u16* msg   = take((size_t)NTOK * DIM * 2);  // 24 MiB

    // weight transposes + cast: f32 (K,N) -> bf16 (N,K)
    transpose_f2b<<<dim3(HID / 32, DIM / 32), 256, 0, stream>>>(W1, W1T, DIM, HID);
    transpose_f2b<<<dim3(DIM / 32, HID / 32), 256, 0, stream>>>(W2, W2T, HID, DIM);
    transpose_f2b<<<dim3(HID / 32, DIM / 32), 256, 0, stream>>>(W3, W3T, DIM, HID);
    transpose_f2b<<<dim3(DIM / 32, HID / 32), 256, 0, stream>>>(W4, W4T, HID, DIM);
    transpose_f2b<<<dim3(DIM / 32, DIM / 32), 256, 0, stream>>>(W5, W5T, DIM, DIM);

    embed_kernel<<<NTOK / 4, 256, 0, stream>>>(element, aroma, charge, segment, pe,
                                               E_elem, E_charge, E_aroma, E_seg,
                                               emb32, emb16);

    // fused MLP: xa = emb32 + relu(emb@W1+b1)@W2+b2
    //            msg = (xa + relu(xa@W3+b3)@W4+b4) @ W5 + b5
    ffn_fused<<<NTOK / PM, 512, 0, stream>>>(emb16, emb32, W1T, b1, W2T, b2,
                                             nullptr, nullptr, xa);
    ffn_fused<<<NTOK / PM, 512, 0, stream>>>(xa, nullptr, W3T, b3, W4T, b4,
                                             W5T, b5, msg);

    agg_kernel<<<NTOK / 4, 256, 0, stream>>>(emb32, msg, bond, (float*)d_out);
}

// Round 12
// 480.777 us; speedup vs baseline: 2.0992x; 2.0992x over previous
//
#include <hip/hip_runtime.h>
#include <cstdint>
#include <cstddef>

typedef unsigned short u16;
typedef unsigned int u32;

typedef unsigned short u16x8 __attribute__((ext_vector_type(8)));
typedef __bf16 bf16x8 __attribute__((ext_vector_type(8)));
typedef float f32x4 __attribute__((ext_vector_type(4)));
typedef float f32x8 __attribute__((ext_vector_type(8)));

#define NB   128
#define NL   192
#define NTOK (NB * NL)   // 24576
#define DIM  512
#define HID  2048

static __device__ __forceinline__ float bf2f(u16 h) {
    union { u32 u; float f; } v; v.u = ((u32)h) << 16; return v.f;
}
static __device__ __forceinline__ u16 f2bf(float f) {
    union { float f; u32 u; } v; v.f = f;
    u32 u = v.u + 0x7FFF + ((v.u >> 16) & 1);  // RNE
    return (u16)(u >> 16);
}

// -------- all 5 weight transposes in ONE launch: f32 (K,N) -> bf16 (N,K) ----
// ranges: [0,1024) W1 (K=512,N=2048); [1024,2048) W2 (K=2048,N=512);
// [2048,3072) W3; [3072,4096) W4; [4096,4352) W5 (512x512).
__global__ void transpose_all(const float* __restrict__ W1, u16* __restrict__ W1T,
                              const float* __restrict__ W2, u16* __restrict__ W2T,
                              const float* __restrict__ W3, u16* __restrict__ W3T,
                              const float* __restrict__ W4, u16* __restrict__ W4T,
                              const float* __restrict__ W5, u16* __restrict__ W5T) {
    int bid = blockIdx.x;
    const float* in; u16* out; int K, N, t;
    if (bid < 1024)      { in = W1; out = W1T; K = DIM; N = HID; t = bid; }
    else if (bid < 2048) { in = W2; out = W2T; K = HID; N = DIM; t = bid - 1024; }
    else if (bid < 3072) { in = W3; out = W3T; K = DIM; N = HID; t = bid - 2048; }
    else if (bid < 4096) { in = W4; out = W4T; K = HID; N = DIM; t = bid - 3072; }
    else                 { in = W5; out = W5T; K = DIM; N = DIM; t = bid - 4096; }
    const int nx = N >> 5;
    const int n0 = (t % nx) * 32, k0 = (t / nx) * 32;
    __shared__ float tile[32][33];
    int tx = threadIdx.x & 31, ty = threadIdx.x >> 5;  // 32 x 8
#pragma unroll
    for (int i = 0; i < 4; i++)
        tile[ty + i * 8][tx] = in[(size_t)(k0 + ty + i * 8) * N + n0 + tx];
    __syncthreads();
#pragma unroll
    for (int i = 0; i < 4; i++)
        out[(size_t)(n0 + ty + i * 8) * K + k0 + tx] = f2bf(tile[tx][ty + i * 8]);
}

// -------- embedding: emb[t=l*B+b][d] = sum of 5 f32 tables; f32 + bf16 out ----
static __device__ __forceinline__ void add8f(float* acc, const float* p) {
    f32x8 v = *(const f32x8*)p;
#pragma unroll
    for (int i = 0; i < 8; i++) acc[i] += v[i];
}

__global__ void embed_kernel(const int* __restrict__ element, const int* __restrict__ aroma,
                             const int* __restrict__ charge, const int* __restrict__ segment,
                             const float* __restrict__ pe, const float* __restrict__ E_elem,
                             const float* __restrict__ E_charge, const float* __restrict__ E_aroma,
                             const float* __restrict__ E_seg,
                             float* __restrict__ emb32, u16* __restrict__ emb16) {
    int t = blockIdx.x * 4 + (threadIdx.x >> 6);  // one wave per token
    int lane = threadIdx.x & 63;
    int l = t >> 7, b = t & 127;                  // t = l*128 + b
    int d = lane * 8;
    int idx = b * NL + l;
    int e = element[idx];
    int a = aroma[idx];
    int c = charge[idx] + 6;
    int s = segment[idx];
    float acc[8] = {0, 0, 0, 0, 0, 0, 0, 0};
    add8f(acc, E_elem  + (size_t)e * DIM + d);
    add8f(acc, pe      + (size_t)l * DIM + d);
    add8f(acc, E_aroma + (size_t)a * DIM + d);
    add8f(acc, E_charge+ (size_t)c * DIM + d);
    add8f(acc, E_seg   + (size_t)s * DIM + d);
    f32x8 o32; u16x8 o16;
#pragma unroll
    for (int i = 0; i < 8; i++) { o32[i] = acc[i]; o16[i] = f2bf(acc[i]); }
    *(f32x8*)(emb32 + (size_t)t * DIM + d) = o32;
    *(u16x8*)(emb16 + (size_t)t * DIM + d) = o16;
}

// -------- GEMM: C[M,N] = A[M,K] @ BT[N,K]^T (+f32 bias, relu, bf16/f32 resid) --
// Round-3 structure (best verified across 8 variants): 256x256 tile, BK=64,
// double-buffered LDS (128 KB), 512 threads = 8 waves (2M x 4N), per-wave
// 128x64 = acc[8][4]. ONE barrier per 64-K tile: {vmcnt(0); s_barrier; issue
// all 8 GLL for t+1; 24 ds_read_b128 + 64 MFMA as a single compiler-scheduled
// region}. Runs at ~572 TF on the big shapes = 94% of the measured 2-phase
// structural ceiling (m233: 607 TF); the 8-phase escape (m201) was ported
// faithfully (r7) and regressed 32% on these shapes (consistent with m232's
// failed 128^2-8ph quadrant), so this structure is the committed one.
// Swizzle: LDS[row][c] holds global chunk c^(row&7) via pre-swizzled source,
// linear GLL dest (m104); reads chunk (s*4+fq)^(fr&7): 0 conflicts (measured).
// Requires M%256==0, N%256==0, K%64==0 (all our shapes: K=512/2048).
__global__ __launch_bounds__(512, 2) void gemm_bt(
    const u16* __restrict__ A, const u16* __restrict__ BT,
    const float* __restrict__ bias, const u16* __restrict__ resid16,
    const float* __restrict__ resid32,
    u16* __restrict__ C, int M, int N, int K, int do_relu) {
    // staging: A[2][256*64] @ 0 (64 KB), B[2][256*64] @ 32768 u16 (64 KB).
    // epilogue reuses smem as [256][264] u16 = 132 KB.
    __shared__ __align__(16) u16 smem[256 * 264];

    const int tid  = threadIdx.x;
    const int wave = tid >> 6;
    const int lane = tid & 63;

    // XCD-aware swizzle (bijective when nwg%8==0 -- all our grids), N-fastest.
    const int nwg = gridDim.x;
    const int bid = blockIdx.x;
    const int wg  = ((nwg & 7) == 0) ? ((bid & 7) * (nwg >> 3) + (bid >> 3)) : bid;
    const int nt  = N >> 8;                 // N-tiles of 256
    const int m0  = (wg / nt) * 256;
    const int n0  = (wg % nt) * 256;

    const int wmh = wave >> 2;          // 0..1 : wave's A row-half (128 rows)
    const int wnq = wave & 3;           // 0..3 : wave's B row-quarter (64 rows)
    const int fr  = lane & 15;          // fragment row/col
    const int fq  = lane >> 4;          // fragment k-quad
    // swizzled read chunks (u16 offsets) for k-slot 0 / 1
    const int ck0 = ((fq ^ (fr & 7)) * 8);
    const int ck1 = (((4 | fq) ^ (fr & 7)) * 8);   // 4+fq == 4|fq for fq<4

    // staging: 8 threads per row (8 chunks of 8 u16), 64 rows per GLL round.
    const int sRow = tid >> 3;                       // 0..63
    const int sChk = ((tid & 7) ^ (sRow & 7)) * 8;   // pre-swizzled SOURCE chunk
    const int ldst = sRow * 64 + (tid & 7) * 8;      // LINEAR lds dest (u16)

    const u16* Asrc = A  + (size_t)(m0 + sRow) * K + sChk;
    const u16* Bsrc = BT + (size_t)(n0 + sRow) * K + sChk;

    f32x4 acc[8][4] = {};

#define GLL(gp, lp) __builtin_amdgcn_global_load_lds(                            \
        (const __attribute__((address_space(1))) void*)(gp),                     \
        (__attribute__((address_space(3))) void*)(lp), 16, 0, 0)
#define STAGE(buf, kt) do {                                                      \
    GLL(Asrc + (size_t)(kt) * 64,                 &smem[(buf)*16384 +        ldst]); \
    GLL(Bsrc + (size_t)(kt) * 64,                 &smem[32768 + (buf)*16384 +        ldst]); \
    GLL(Asrc + (size_t)(kt) * 64 + (size_t) 64*K, &smem[(buf)*16384 +  4096 + ldst]); \
    GLL(Bsrc + (size_t)(kt) * 64 + (size_t) 64*K, &smem[32768 + (buf)*16384 +  4096 + ldst]); \
    GLL(Asrc + (size_t)(kt) * 64 + (size_t)128*K, &smem[(buf)*16384 +  8192 + ldst]); \
    GLL(Bsrc + (size_t)(kt) * 64 + (size_t)128*K, &smem[32768 + (buf)*16384 +  8192 + ldst]); \
    GLL(Asrc + (size_t)(kt) * 64 + (size_t)192*K, &smem[(buf)*16384 + 12288 + ldst]); \
    GLL(Bsrc + (size_t)(kt) * 64 + (size_t)192*K, &smem[32768 + (buf)*16384 + 12288 + ldst]); \
} while (0)

    const int nk = K >> 6;   // 8 or 32 here
    STAGE(0, 0);             // tile 0 in flight (8 GLL)

    for (int t = 0; t < nk; ++t) {
        // boundary: tile t's 8 loads are the only outstanding vmem; the wait
        // is a full tile after their issue, so it is (nearly) free.
        asm volatile("s_waitcnt vmcnt(0)\n\ts_barrier" ::: "memory");
        if (t + 1 < nk) STAGE((t + 1) & 1, t + 1);   // in flight across tile t

        const u16* Ab = &smem[(t & 1) * 16384];
        const u16* Bb = &smem[32768 + (t & 1) * 16384];
#pragma unroll
        for (int s = 0; s < 2; ++s) {
            const int ck = s ? ck1 : ck0;
            bf16x8 af[8], bg[4];
#pragma unroll
            for (int i = 0; i < 8; ++i)
                af[i] = *(const bf16x8*)(&Ab[(wmh * 128 + i * 16 + fr) * 64 + ck]);
#pragma unroll
            for (int j = 0; j < 4; ++j)
                bg[j] = *(const bf16x8*)(&Bb[(wnq * 64 + j * 16 + fr) * 64 + ck]);

            __builtin_amdgcn_s_setprio(1);
#pragma unroll
            for (int i = 0; i < 8; ++i)
#pragma unroll
                for (int j = 0; j < 4; ++j)
                    acc[i][j] = __builtin_amdgcn_mfma_f32_16x16x32_bf16(
                        af[i], bg[j], acc[i][j], 0, 0, 0);
            __builtin_amdgcn_s_setprio(0);
        }
    }
#undef STAGE
#undef GLL

    // ---- epilogue: bias/relu/resid in-register, stage bf16 tile to LDS, ----
    // ---- then fully-coalesced dwordx4 stores. ------------------------------
    // C/D layout: col = lane&15 (n), row = (lane>>4)*4 + reg (m)
    __syncthreads();   // all waves past final LDS reads; all vmem drained
#define CSTR 264       // 256 + 8 u16 pad
#pragma unroll
    for (int j = 0; j < 4; j++) {
        int n = n0 + wnq * 64 + j * 16 + fr;
        float bv = bias[n];
#pragma unroll
        for (int i = 0; i < 8; i++) {
#pragma unroll
            for (int r = 0; r < 4; r++) {
                int m = m0 + wmh * 128 + i * 16 + fq * 4 + r;
                float v = acc[i][j][r] + bv;
                if (do_relu) v = fmaxf(v, 0.0f);
                if (resid16) v += bf2f(resid16[(size_t)m * N + n]);
                if (resid32) v += resid32[(size_t)m * N + n];
                smem[(wmh * 128 + i * 16 + fq * 4 + r) * CSTR + wnq * 64 + j * 16 + fr] = f2bf(v);
            }
        }
    }
    __syncthreads();
    {
        const int erow = tid >> 5;         // 0..15
        const int ecol = (tid & 31) * 8;   // 32 lanes x 8 u16 = 256 cols
#pragma unroll
        for (int rr = 0; rr < 16; ++rr) {
            int row = rr * 16 + erow;
            *(u16x8*)(C + (size_t)(m0 + row) * N + n0 + ecol) =
                *(const u16x8*)(&smem[row * CSTR + ecol]);
        }
    }
#undef CSTR
}

// -------- aggregation + final residual (in-place on d_out, f32) --------
// out[t=l*B+b][d] = emb32[t][d] + sum_m (bond[b,l,m]!=l) * msg[bond*B+b][d]
__global__ void agg_kernel(const float* __restrict__ emb32, const u16* __restrict__ msg,
                           const int* __restrict__ bond, float* __restrict__ out) {
    int t = blockIdx.x * 4 + (threadIdx.x >> 6);  // one wave per token
    int lane = threadIdx.x & 63;
    int l = t >> 7, b = t & 127;
    int d = lane * 8;
    float acc[8];
    {
        f32x8 v = *(const f32x8*)(emb32 + (size_t)t * DIM + d);
#pragma unroll
        for (int i = 0; i < 8; i++) acc[i] = v[i];
    }
    const int* bp = bond + ((size_t)b * NL + l) * 6;
#pragma unroll
    for (int m = 0; m < 6; m++) {
        int j = bp[m];
        if (j != l) {  // wave-uniform branch
            u16x8 g = *(const u16x8*)(msg + ((size_t)j * NB + b) * DIM + d);
#pragma unroll
            for (int i = 0; i < 8; i++) acc[i] += bf2f(g[i]);
        }
    }
    f32x8 o;
#pragma unroll
    for (int i = 0; i < 8; i++) o[i] = acc[i];
    *(f32x8*)(out + (size_t)t * DIM + d) = o;
}

extern "C" void kernel_launch(void* const* d_in, const int* in_sizes, int n_in,
                              void* d_out, int out_size, void* d_ws, size_t ws_size,
                              hipStream_t stream) {
    const int* element = (const int*)d_in[0];
    const int* bond    = (const int*)d_in[1];
    const int* aroma   = (const int*)d_in[2];
    const int* charge  = (const int*)d_in[3];
    const int* segment = (const int*)d_in[4];
    const float* pe      = (const float*)d_in[5];
    const float* E_elem  = (const float*)d_in[6];
    const float* E_charge= (const float*)d_in[7];
    const float* E_aroma = (const float*)d_in[8];
    const float* E_seg   = (const float*)d_in[9];
    const float* W1 = (const float*)d_in[10];
    const float* b1 = (const float*)d_in[11];
    const float* W2 = (const float*)d_in[12];
    const float* b2 = (const float*)d_in[13];
    const float* W3 = (const float*)d_in[14];
    const float* b3 = (const float*)d_in[15];
    const float* W4 = (const float*)d_in[16];
    const float* b4 = (const float*)d_in[17];
    const float* W5 = (const float*)d_in[18];
    const float* b5 = (const float*)d_in[19];

    // f32 emb lives in d_out (50 MiB); agg rewrites d_out in place at the end.
    float* emb32 = (float*)d_out;

    // dynamic ws layout — never exceed ws_size
    char* ws = (char*)d_ws;
    size_t woff = 0;
    auto take = [&](size_t bytes) -> u16* {
        u16* p = (u16*)(ws + woff);
        woff += (bytes + 255) & ~(size_t)255;
        return p;
    };
    u16* W1T = take((size_t)HID * DIM * 2);   // 2048x512 bf16
    u16* W2T = take((size_t)DIM * HID * 2);   // 512x2048
    u16* W3T = take((size_t)HID * DIM * 2);
    u16* W4T = take((size_t)DIM * HID * 2);
    u16* W5T = take((size_t)DIM * DIM * 2);
    u16* emb16 = take((size_t)NTOK * DIM * 2);  // 24 MiB
    u16* msg   = take((size_t)NTOK * DIM * 2);  // 24 MiB

    // pick largest M-chunk that fits: h(CM x HID) + xa,xb(CM x DIM), bf16.
    // CM must be a multiple of 256 (gemm tile height).
    static const int ncs[] = {1, 2, 3, 4, 6, 8, 12, 16, 24, 32, 48, 96};
    int CM = 256;
    for (int nc : ncs) {
        int cm = NTOK / nc;
        if (cm % 256 != 0) continue;
        size_t need = woff + ((size_t)cm * HID * 2 + 256)
                           + ((size_t)cm * DIM * 2 + 256) * 2;
        if (need <= ws_size) { CM = cm; break; }
    }
    u16* hC  = take((size_t)CM * HID * 2);
    u16* xaC = take((size_t)CM * DIM * 2);
    u16* xbC = take((size_t)CM * DIM * 2);

    // all 5 weight transposes in one launch (was 5 serialized small launches)
    transpose_all<<<4352, 256, 0, stream>>>(W1, W1T, W2, W2T, W3, W3T,
                                            W4, W4T, W5, W5T);

    embed_kernel<<<NTOK / 4, 256, 0, stream>>>(element, aroma, charge, segment, pe,
                                               E_elem, E_charge, E_aroma, E_seg,
                                               emb32, emb16);

    // MLP per M-chunk: x += relu(x@W1+b1)@W2+b2 ; x += relu(x@W3+b3)@W4+b4 ; msg = x@W5+b5
    for (int c0 = 0; c0 < NTOK; c0 += CM) {
        const u16* x16 = emb16 + (size_t)c0 * DIM;
        const float* x32 = emb32 + (size_t)c0 * DIM;
        u16* msgC = msg + (size_t)c0 * DIM;
        int mt = CM / 256;
        gemm_bt<<<dim3(mt * (HID / 256)), 512, 0, stream>>>(x16, W1T, b1, nullptr, nullptr, hC,  CM, HID, DIM, 1);
        gemm_bt<<<dim3(mt * (DIM / 256)), 512, 0, stream>>>(hC,  W2T, b2, nullptr, x32,     xaC, CM, DIM, HID, 0);
        gemm_bt<<<dim3(mt * (HID / 256)), 512, 0, stream>>>(xaC, W3T, b3, nullptr, nullptr, hC,  CM, HID, DIM, 1);
        gemm_bt<<<dim3(mt * (DIM / 256)), 512, 0, stream>>>(hC,  W4T, b4, xaC,    nullptr,  xbC, CM, DIM, HID, 0);
        gemm_bt<<<dim3(mt * (DIM / 256)), 512, 0, stream>>>(xbC, W5T, b5, nullptr, nullptr, msgC, CM, DIM, DIM, 0);
    }

    agg_kernel<<<NTOK / 4, 256, 0, stream>>>(emb32, msg, bond, (float*)d_out);
}

// Round 13
// 453.194 us; speedup vs baseline: 2.2270x; 1.0609x over previous
//
#include <hip/hip_runtime.h>
#include <cstdint>
#include <cstddef>

typedef unsigned short u16;
typedef unsigned int u32;

typedef unsigned short u16x8 __attribute__((ext_vector_type(8)));
typedef __bf16 bf16x8 __attribute__((ext_vector_type(8)));
typedef float f32x4 __attribute__((ext_vector_type(4)));
typedef float f32x8 __attribute__((ext_vector_type(8)));

#define NB   128
#define NL   192
#define NTOK (NB * NL)   // 24576
#define DIM  512
#define HID  2048

static __device__ __forceinline__ float bf2f(u16 h) {
    union { u32 u; float f; } v; v.u = ((u32)h) << 16; return v.f;
}
static __device__ __forceinline__ u16 f2bf(float f) {
    union { float f; u32 u; } v; v.f = f;
    u32 u = v.u + 0x7FFF + ((v.u >> 16) & 1);  // RNE
    return (u16)(u >> 16);
}

// -------- all 5 weight transposes in ONE launch: f32 (K,N) -> bf16 (N,K) ----
__global__ void transpose_all(const float* __restrict__ W1, u16* __restrict__ W1T,
                              const float* __restrict__ W2, u16* __restrict__ W2T,
                              const float* __restrict__ W3, u16* __restrict__ W3T,
                              const float* __restrict__ W4, u16* __restrict__ W4T,
                              const float* __restrict__ W5, u16* __restrict__ W5T) {
    int bid = blockIdx.x;
    const float* in; u16* out; int K, N, t;
    if (bid < 1024)      { in = W1; out = W1T; K = DIM; N = HID; t = bid; }
    else if (bid < 2048) { in = W2; out = W2T; K = HID; N = DIM; t = bid - 1024; }
    else if (bid < 3072) { in = W3; out = W3T; K = DIM; N = HID; t = bid - 2048; }
    else if (bid < 4096) { in = W4; out = W4T; K = HID; N = DIM; t = bid - 3072; }
    else                 { in = W5; out = W5T; K = DIM; N = DIM; t = bid - 4096; }
    const int nx = N >> 5;
    const int n0 = (t % nx) * 32, k0 = (t / nx) * 32;
    __shared__ float tile[32][33];
    int tx = threadIdx.x & 31, ty = threadIdx.x >> 5;  // 32 x 8
#pragma unroll
    for (int i = 0; i < 4; i++)
        tile[ty + i * 8][tx] = in[(size_t)(k0 + ty + i * 8) * N + n0 + tx];
    __syncthreads();
#pragma unroll
    for (int i = 0; i < 4; i++)
        out[(size_t)(n0 + ty + i * 8) * K + k0 + tx] = f2bf(tile[tx][ty + i * 8]);
}

// -------- embedding: emb16[t=l*B+b][d] = bf16(sum of 5 f32 tables) ----
// emb32 eliminated (round 13): the f32 residual copy cost ~100 MB of HBM
// across embed/W2/agg; bf16 residual adds <=0.2% relative error on a term
// already bf16-dominated (absmax 0.031 vs threshold 0.151).
static __device__ __forceinline__ void add8f(float* acc, const float* p) {
    f32x8 v = *(const f32x8*)p;
#pragma unroll
    for (int i = 0; i < 8; i++) acc[i] += v[i];
}

__global__ void embed_kernel(const int* __restrict__ element, const int* __restrict__ aroma,
                             const int* __restrict__ charge, const int* __restrict__ segment,
                             const float* __restrict__ pe, const float* __restrict__ E_elem,
                             const float* __restrict__ E_charge, const float* __restrict__ E_aroma,
                             const float* __restrict__ E_seg,
                             u16* __restrict__ emb16) {
    int t = blockIdx.x * 4 + (threadIdx.x >> 6);  // one wave per token
    int lane = threadIdx.x & 63;
    int l = t >> 7, b = t & 127;                  // t = l*128 + b
    int d = lane * 8;
    int idx = b * NL + l;
    int e = element[idx];
    int a = aroma[idx];
    int c = charge[idx] + 6;
    int s = segment[idx];
    float acc[8] = {0, 0, 0, 0, 0, 0, 0, 0};
    add8f(acc, E_elem  + (size_t)e * DIM + d);
    add8f(acc, pe      + (size_t)l * DIM + d);
    add8f(acc, E_aroma + (size_t)a * DIM + d);
    add8f(acc, E_charge+ (size_t)c * DIM + d);
    add8f(acc, E_seg   + (size_t)s * DIM + d);
    u16x8 o16;
#pragma unroll
    for (int i = 0; i < 8; i++) o16[i] = f2bf(acc[i]);
    *(u16x8*)(emb16 + (size_t)t * DIM + d) = o16;
}

// -------- GEMM: C[M,N] = A[M,K] @ BT[N,K]^T (+f32 bias, relu, bf16 resid) ----
// Round-13 = round-3 structure + 3-deep A staging (2-tile lead, counted wait).
// Rationale: per K-tile the block has ~650 cy of coverable work between
// boundaries, but the A stream (hC, 100 MB, L3/HBM-miss) has ~900 cy latency
// and round-3 issued its loads only 1 tile (~650 cy) ahead -> ~250 cy hard
// stall at every boundary (the measured 22% MfmaUtil). A now leads 2 tiles
// (~1300 cy > 900); B (2 MB L2-hot weights, ~200 cy) keeps the proven 1-tile
// lead. Round-5's "counted-wait regression" confounded this with a tile-size
// change; this is the clean experiment.
//   LDS: A[3][256*64] @ 0 (96 KB) + B[2][256*64] @ 49152 u16 (64 KB) = 160 KB
//   (full pool; AITER's gfx950 fmha runs 160 KB workgroups). Epilogue reuses
//   smem[0..67584) as [256][264] u16 = 132 KB.
// vmcnt ledger (4 GLL per stage; issue order inside tile t: B(t+1), A(t+2)):
//   outstanding before wait at tile t: {A(t)[@t-2], B(t)[@t-1], A(t+1)[@t-1]}
//   -> vmcnt(4) retires A(t),B(t), leaves A(t+1) IN FLIGHT (never drains
//   in-loop).  t=0: prologue {A0,B0,A1} -> same.  t=nk-2: issue B(nk-1),
//   skip A(nk) -> t=nk-1 outstanding {A,B}(nk-1) -> vmcnt(0).
// Buffer safety: A(t+2)->buf (t+2)%3 = (t-1)%3, whose reader (tile t-1)
//   finished its ds_reads before the t-boundary barrier that precedes this
//   stage's issue; B(t+1)->buf (t+1)&1 = (t-1)&1, same argument.
// Swizzle (proven 0-conflict): LDS[row][c] holds global chunk c^(row&7) via
//   pre-swizzled source, linear GLL dest; reads chunk (s*4+fq)^(fr&7).
// Requires M%256==0, N%256==0, K%64==0, K/64>=2 (all our shapes).
__global__ __launch_bounds__(512, 2) void gemm_bt(
    const u16* __restrict__ A, const u16* __restrict__ BT,
    const float* __restrict__ bias, const u16* __restrict__ resid16,
    u16* __restrict__ C, int M, int N, int K, int do_relu) {
    __shared__ __align__(16) u16 smem[81920];   // 160 KB

    const int tid  = threadIdx.x;
    const int wave = tid >> 6;
    const int lane = tid & 63;

    // XCD-aware swizzle (bijective when nwg%8==0 -- all our grids), N-fastest.
    const int nwg = gridDim.x;
    const int bid = blockIdx.x;
    const int wg  = ((nwg & 7) == 0) ? ((bid & 7) * (nwg >> 3) + (bid >> 3)) : bid;
    const int nt  = N >> 8;                 // N-tiles of 256
    const int m0  = (wg / nt) * 256;
    const int n0  = (wg % nt) * 256;

    const int wmh = wave >> 2;          // 0..1 : wave's A row-half (128 rows)
    const int wnq = wave & 3;           // 0..3 : wave's B row-quarter (64 rows)
    const int fr  = lane & 15;          // fragment row/col
    const int fq  = lane >> 4;          // fragment k-quad
    const int ck0 = ((fq ^ (fr & 7)) * 8);         // swizzled read chunk, ks=0
    const int ck1 = (((4 | fq) ^ (fr & 7)) * 8);   // ks=1

    // staging: 8 threads per row (8 chunks of 8 u16), 64 rows per GLL round.
    const int sRow = tid >> 3;                       // 0..63
    const int sChk = ((tid & 7) ^ (sRow & 7)) * 8;   // pre-swizzled SOURCE chunk
    const int ldst = sRow * 64 + (tid & 7) * 8;      // LINEAR lds dest (u16)

    const u16* Asrc = A  + (size_t)(m0 + sRow) * K + sChk;
    const u16* Bsrc = BT + (size_t)(n0 + sRow) * K + sChk;

    f32x4 acc[8][4] = {};

#define GLL(gp, lp) __builtin_amdgcn_global_load_lds(                            \
        (const __attribute__((address_space(1))) void*)(gp),                     \
        (__attribute__((address_space(3))) void*)(lp), 16, 0, 0)
#define STAGE_A(buf, kt) do {                                                    \
    GLL(Asrc + (size_t)(kt) * 64,                 &smem[(buf)*16384 +         ldst]); \
    GLL(Asrc + (size_t)(kt) * 64 + (size_t) 64*K, &smem[(buf)*16384 +  4096 + ldst]); \
    GLL(Asrc + (size_t)(kt) * 64 + (size_t)128*K, &smem[(buf)*16384 +  8192 + ldst]); \
    GLL(Asrc + (size_t)(kt) * 64 + (size_t)192*K, &smem[(buf)*16384 + 12288 + ldst]); \
} while (0)
#define STAGE_B(buf, kt) do {                                                    \
    GLL(Bsrc + (size_t)(kt) * 64,                 &smem[49152 + (buf)*16384 +         ldst]); \
    GLL(Bsrc + (size_t)(kt) * 64 + (size_t) 64*K, &smem[49152 + (buf)*16384 +  4096 + ldst]); \
    GLL(Bsrc + (size_t)(kt) * 64 + (size_t)128*K, &smem[49152 + (buf)*16384 +  8192 + ldst]); \
    GLL(Bsrc + (size_t)(kt) * 64 + (size_t)192*K, &smem[49152 + (buf)*16384 + 12288 + ldst]); \
} while (0)

    const int nk = K >> 6;   // 8 or 32 here (>= 2)
    STAGE_A(0, 0); STAGE_B(0, 0); STAGE_A(1, 1);   // 12 loads in flight

    int bt3 = 0;             // t % 3 (A buffer)
    for (int t = 0; t < nk; ++t) {
        // counted wait: A(t),B(t) landed; A(t+1) stays in flight.
        if (t < nk - 1)
            asm volatile("s_waitcnt vmcnt(4)\n\ts_barrier" ::: "memory");
        else
            asm volatile("s_waitcnt vmcnt(0)\n\ts_barrier" ::: "memory");
        if (t + 1 < nk) STAGE_B((t + 1) & 1, t + 1);     // issue B first (older)
        if (t + 2 < nk) {
            int a3 = bt3 + 2; if (a3 >= 3) a3 -= 3;
            STAGE_A(a3, t + 2);                          // 2-tile A lead
        }

        const u16* Ab = &smem[bt3 * 16384];
        const u16* Bb = &smem[49152 + (t & 1) * 16384];
#pragma unroll
        for (int s = 0; s < 2; ++s) {
            const int ck = s ? ck1 : ck0;
            bf16x8 af[8], bg[4];
#pragma unroll
            for (int i = 0; i < 8; ++i)
                af[i] = *(const bf16x8*)(&Ab[(wmh * 128 + i * 16 + fr) * 64 + ck]);
#pragma unroll
            for (int j = 0; j < 4; ++j)
                bg[j] = *(const bf16x8*)(&Bb[(wnq * 64 + j * 16 + fr) * 64 + ck]);

            __builtin_amdgcn_s_setprio(1);
#pragma unroll
            for (int i = 0; i < 8; ++i)
#pragma unroll
                for (int j = 0; j < 4; ++j)
                    acc[i][j] = __builtin_amdgcn_mfma_f32_16x16x32_bf16(
                        af[i], bg[j], acc[i][j], 0, 0, 0);
            __builtin_amdgcn_s_setprio(0);
        }
        bt3 = (bt3 == 2) ? 0 : bt3 + 1;
    }
#undef STAGE_A
#undef STAGE_B
#undef GLL

    // ---- epilogue: bias/relu/resid in-register, stage bf16 tile to LDS, ----
    // ---- then fully-coalesced dwordx4 stores. ------------------------------
    // C/D layout: col = lane&15 (n), row = (lane>>4)*4 + reg (m)
    __syncthreads();   // all waves past final LDS reads; all vmem drained
#define CSTR 264       // 256 + 8 u16 pad
#pragma unroll
    for (int j = 0; j < 4; j++) {
        int n = n0 + wnq * 64 + j * 16 + fr;
        float bv = bias[n];
#pragma unroll
        for (int i = 0; i < 8; i++) {
#pragma unroll
            for (int r = 0; r < 4; r++) {
                int m = m0 + wmh * 128 + i * 16 + fq * 4 + r;
                float v = acc[i][j][r] + bv;
                if (do_relu) v = fmaxf(v, 0.0f);
                if (resid16) v += bf2f(resid16[(size_t)m * N + n]);
                smem[(wmh * 128 + i * 16 + fq * 4 + r) * CSTR + wnq * 64 + j * 16 + fr] = f2bf(v);
            }
        }
    }
    __syncthreads();
    {
        const int erow = tid >> 5;         // 0..15
        const int ecol = (tid & 31) * 8;   // 32 lanes x 8 u16 = 256 cols
#pragma unroll
        for (int rr = 0; rr < 16; ++rr) {
            int row = rr * 16 + erow;
            *(u16x8*)(C + (size_t)(m0 + row) * N + n0 + ecol) =
                *(const u16x8*)(&smem[row * CSTR + ecol]);
        }
    }
#undef CSTR
}

// -------- aggregation + final residual (f32 out) --------
// out[t=l*B+b][d] = emb16[t][d] + sum_m (bond[b,l,m]!=l) * msg[bond*B+b][d]
__global__ void agg_kernel(const u16* __restrict__ emb16, const u16* __restrict__ msg,
                           const int* __restrict__ bond, float* __restrict__ out) {
    int t = blockIdx.x * 4 + (threadIdx.x >> 6);  // one wave per token
    int lane = threadIdx.x & 63;
    int l = t >> 7, b = t & 127;
    int d = lane * 8;
    float acc[8];
    {
        u16x8 v = *(const u16x8*)(emb16 + (size_t)t * DIM + d);
#pragma unroll
        for (int i = 0; i < 8; i++) acc[i] = bf2f(v[i]);
    }
    const int* bp = bond + ((size_t)b * NL + l) * 6;
#pragma unroll
    for (int m = 0; m < 6; m++) {
        int j = bp[m];
        if (j != l) {  // wave-uniform branch
            u16x8 g = *(const u16x8*)(msg + ((size_t)j * NB + b) * DIM + d);
#pragma unroll
            for (int i = 0; i < 8; i++) acc[i] += bf2f(g[i]);
        }
    }
    f32x8 o;
#pragma unroll
    for (int i = 0; i < 8; i++) o[i] = acc[i];
    *(f32x8*)(out + (size_t)t * DIM + d) = o;
}

extern "C" void kernel_launch(void* const* d_in, const int* in_sizes, int n_in,
                              void* d_out, int out_size, void* d_ws, size_t ws_size,
                              hipStream_t stream) {
    const int* element = (const int*)d_in[0];
    const int* bond    = (const int*)d_in[1];
    const int* aroma   = (const int*)d_in[2];
    const int* charge  = (const int*)d_in[3];
    const int* segment = (const int*)d_in[4];
    const float* pe      = (const float*)d_in[5];
    const float* E_elem  = (const float*)d_in[6];
    const float* E_charge= (const float*)d_in[7];
    const float* E_aroma = (const float*)d_in[8];
    const float* E_seg   = (const float*)d_in[9];
    const float* W1 = (const float*)d_in[10];
    const float* b1 = (const float*)d_in[11];
    const float* W2 = (const float*)d_in[12];
    const float* b2 = (const float*)d_in[13];
    const float* W3 = (const float*)d_in[14];
    const float* b3 = (const float*)d_in[15];
    const float* W4 = (const float*)d_in[16];
    const float* b4 = (const float*)d_in[17];
    const float* W5 = (const float*)d_in[18];
    const float* b5 = (const float*)d_in[19];

    // dynamic ws layout — never exceed ws_size
    char* ws = (char*)d_ws;
    size_t woff = 0;
    auto take = [&](size_t bytes) -> u16* {
        u16* p = (u16*)(ws + woff);
        woff += (bytes + 255) & ~(size_t)255;
        return p;
    };
    u16* W1T = take((size_t)HID * DIM * 2);   // 2048x512 bf16
    u16* W2T = take((size_t)DIM * HID * 2);   // 512x2048
    u16* W3T = take((size_t)HID * DIM * 2);
    u16* W4T = take((size_t)DIM * HID * 2);
    u16* W5T = take((size_t)DIM * DIM * 2);
    u16* emb16 = take((size_t)NTOK * DIM * 2);  // 24 MiB
    u16* msg   = take((size_t)NTOK * DIM * 2);  // 24 MiB

    // pick largest M-chunk that fits: h(CM x HID) + xa,xb(CM x DIM), bf16.
    static const int ncs[] = {1, 2, 3, 4, 6, 8, 12, 16, 24, 32, 48, 96};
    int CM = 256;
    for (int nc : ncs) {
        int cm = NTOK / nc;
        if (cm % 256 != 0) continue;
        size_t need = woff + ((size_t)cm * HID * 2 + 256)
                           + ((size_t)cm * DIM * 2 + 256) * 2;
        if (need <= ws_size) { CM = cm; break; }
    }
    u16* hC  = take((size_t)CM * HID * 2);
    u16* xaC = take((size_t)CM * DIM * 2);
    u16* xbC = take((size_t)CM * DIM * 2);

    // all 5 weight transposes in one launch
    transpose_all<<<4352, 256, 0, stream>>>(W1, W1T, W2, W2T, W3, W3T,
                                            W4, W4T, W5, W5T);

    embed_kernel<<<NTOK / 4, 256, 0, stream>>>(element, aroma, charge, segment, pe,
                                               E_elem, E_charge, E_aroma, E_seg,
                                               emb16);

    // MLP per M-chunk: x += relu(x@W1+b1)@W2+b2 ; x += relu(x@W3+b3)@W4+b4 ; msg = x@W5+b5
    for (int c0 = 0; c0 < NTOK; c0 += CM) {
        const u16* x16 = emb16 + (size_t)c0 * DIM;
        u16* msgC = msg + (size_t)c0 * DIM;
        int mt = CM / 256;
        gemm_bt<<<dim3(mt * (HID / 256)), 512, 0, stream>>>(x16, W1T, b1, nullptr, hC,  CM, HID, DIM, 1);
        gemm_bt<<<dim3(mt * (DIM / 256)), 512, 0, stream>>>(hC,  W2T, b2, x16,    xaC, CM, DIM, HID, 0);
        gemm_bt<<<dim3(mt * (HID / 256)), 512, 0, stream>>>(xaC, W3T, b3, nullptr, hC,  CM, HID, DIM, 1);
        gemm_bt<<<dim3(mt * (DIM / 256)), 512, 0, stream>>>(hC,  W4T, b4, xaC,    xbC, CM, DIM, HID, 0);
        gemm_bt<<<dim3(mt * (DIM / 256)), 512, 0, stream>>>(xbC, W5T, b5, nullptr, msgC, CM, DIM, DIM, 0);
    }

    agg_kernel<<<NTOK / 4, 256, 0, stream>>>(emb16, msg, bond, (float*)d_out);
}